// Round 8
// baseline (803.143 us; speedup 1.0000x reference)
//
#include <hip/hip_runtime.h>
#include <math.h>

constexpr int KIN = 128;   // IN_F

// ---------------- graph setup kernels ----------------

__global__ void count_rank(const int* __restrict__ dst, int* __restrict__ cnt,
                           int* __restrict__ rank, int E) {
    int e = blockIdx.x * blockDim.x + threadIdx.x;
    if (e < E) rank[e] = atomicAdd(&cnt[dst[e]], 1);
}

__global__ void scan_reduce_dinv(const int* __restrict__ cnt, int* __restrict__ bsum,
                                 float* __restrict__ dinv, int n) {
    __shared__ int s[256];
    int t = threadIdx.x;
    int i = blockIdx.x * 256 + t;
    int c = (i < n) ? cnt[i] : 0;
    if (i < n) dinv[i] = 1.0f / sqrtf((float)(c + 1));  // +1 self loop
    s[t] = c;
    __syncthreads();
    for (int off = 128; off > 0; off >>= 1) {
        if (t < off) s[t] += s[t + off];
        __syncthreads();
    }
    if (t == 0) bsum[blockIdx.x] = s[0];
}

__global__ void scan_blocksums(const int* __restrict__ bsum, int* __restrict__ bpre, int nb) {
    __shared__ int s[512];
    int t = threadIdx.x;
    int val = (t < nb) ? bsum[t] : 0;
    s[t] = val;
    __syncthreads();
    for (int off = 1; off < 512; off <<= 1) {
        int x = (t >= off) ? s[t - off] : 0;
        __syncthreads();
        s[t] += x;
        __syncthreads();
    }
    if (t < nb) bpre[t] = s[t] - val;  // exclusive
}

__global__ void scan_scatter(const int* __restrict__ cnt, const int* __restrict__ bpre,
                             int* __restrict__ row_ptr, int n, int total) {
    __shared__ int s[256];
    int t = threadIdx.x;
    int i = blockIdx.x * 256 + t;
    int val = (i < n) ? cnt[i] : 0;
    s[t] = val;
    __syncthreads();
    for (int off = 1; off < 256; off <<= 1) {
        int x = (t >= off) ? s[t - off] : 0;
        __syncthreads();
        s[t] += x;
        __syncthreads();
    }
    if (i < n) row_ptr[i] = bpre[blockIdx.x] + s[t] - val;
    if (i == n - 1) row_ptr[n] = total;
}

__global__ void fill_csr(const int* __restrict__ src, const int* __restrict__ dst,
                         const int* __restrict__ rank, const int* __restrict__ row_ptr,
                         int* __restrict__ csr_src, int E) {
    int e = blockIdx.x * blockDim.x + threadIdx.x;
    if (e < E) {
        int d = dst[e];
        csr_src[row_ptr[d] + rank[e]] = src[e];
    }
}

// ---------------- tiled register-blocked GEMM ----------------
// ATT: writes attention dots TRANSPOSED: a_sT[hd*n+row], a_dT[hd*n+row]
template <int K, int F, int BM, int THREADS, bool SCALE, bool BRELU, bool ATT>
__global__ void __launch_bounds__(THREADS)
gemm_tile(const float* __restrict__ in, const float* __restrict__ W,
          const float* __restrict__ dinv, const float* __restrict__ bias,
          const float* __restrict__ att_src, const float* __restrict__ att_dst,
          float* __restrict__ a_sT, float* __restrict__ a_dT,
          float* __restrict__ out, int n) {
    constexpr int TM = 4, TN = 4;
    constexpr int TX = F / TN;
    constexpr int TY = BM / TM;
    static_assert(THREADS == TX * TY, "thread count mismatch");
    constexpr int K4 = K / 4;
    __shared__ float xs[K][BM];
    __shared__ float Ws[K * F];
    int t = threadIdx.x;
    int row0 = blockIdx.x * BM;

    for (int i = t; i < K * F / 4; i += THREADS)
        ((float4*)Ws)[i] = ((const float4*)W)[i];

    for (int i = t; i < BM * K4; i += THREADS) {
        int r = i % BM, k4 = i / BM;
        int row = row0 + r;
        float4 v = {0.f, 0.f, 0.f, 0.f};
        if (row < n) v = ((const float4*)(in + (size_t)row * K))[k4];
        xs[4 * k4 + 0][r] = v.x;
        xs[4 * k4 + 1][r] = v.y;
        xs[4 * k4 + 2][r] = v.z;
        xs[4 * k4 + 3][r] = v.w;
    }
    __syncthreads();

    int tx = t % TX, ty = t / TX;
    float acc[TM][TN] = {};
#pragma unroll 4
    for (int k = 0; k < K; ++k) {
        float4 xv = *(const float4*)&xs[k][ty * TM];
        float4 wv = *(const float4*)&Ws[k * F + tx * TN];
        float xr[4] = {xv.x, xv.y, xv.z, xv.w};
        float wr[4] = {wv.x, wv.y, wv.z, wv.w};
#pragma unroll
        for (int i = 0; i < TM; ++i)
#pragma unroll
            for (int j = 0; j < TN; ++j)
                acc[i][j] = fmaf(xr[i], wr[j], acc[i][j]);
    }

#pragma unroll
    for (int i = 0; i < TM; ++i) {
        int row = row0 + ty * TM + i;
        if (row >= n) continue;
        float s = SCALE ? dinv[row] : 1.0f;
        float4 o;
        if (BRELU) {
            o.x = fmaxf(fmaf(acc[i][0], s, bias[4 * tx + 0]), 0.f);
            o.y = fmaxf(fmaf(acc[i][1], s, bias[4 * tx + 1]), 0.f);
            o.z = fmaxf(fmaf(acc[i][2], s, bias[4 * tx + 2]), 0.f);
            o.w = fmaxf(fmaf(acc[i][3], s, bias[4 * tx + 3]), 0.f);
        } else {
            o.x = acc[i][0] * s; o.y = acc[i][1] * s;
            o.z = acc[i][2] * s; o.w = acc[i][3] * s;
        }
        ((float4*)(out + (size_t)row * F))[tx] = o;
    }
    if (ATT) {
        int hd = tx >> 2;
        float as0 = att_src[4 * tx + 0], as1 = att_src[4 * tx + 1];
        float as2 = att_src[4 * tx + 2], as3 = att_src[4 * tx + 3];
        float ad0 = att_dst[4 * tx + 0], ad1 = att_dst[4 * tx + 1];
        float ad2 = att_dst[4 * tx + 2], ad3 = att_dst[4 * tx + 3];
#pragma unroll
        for (int i = 0; i < TM; ++i) {
            float ps = acc[i][0] * as0 + acc[i][1] * as1 + acc[i][2] * as2 + acc[i][3] * as3;
            float pd = acc[i][0] * ad0 + acc[i][1] * ad1 + acc[i][2] * ad2 + acc[i][3] * ad3;
            ps += __shfl_xor(ps, 1); pd += __shfl_xor(pd, 1);
            ps += __shfl_xor(ps, 2); pd += __shfl_xor(pd, 2);
            int row = row0 + ty * TM + i;
            if ((tx & 3) == 0 && row < n) {
                a_sT[(size_t)hd * n + row] = ps;
                a_dT[(size_t)hd * n + row] = pd;
            }
        }
    }
}

// ---------------- fused layer2-GEMM + GAT1-GEMM ----------------
__global__ void __launch_bounds__(256)
gemm2_gat(const float* __restrict__ T, const float* __restrict__ W2,
          const float* __restrict__ b2, const float* __restrict__ dinv,
          const float* __restrict__ Wg, const float* __restrict__ att_src,
          const float* __restrict__ att_dst, float* __restrict__ a_sT,
          float* __restrict__ a_dT, float* __restrict__ A1, int n) {
    __shared__ float xs[32][64];
    __shared__ float W2s[32 * 64];
    __shared__ float Wgs[64 * 64];
    __shared__ float hs[64][68];
    int t = threadIdx.x;
    int row0 = blockIdx.x * 64;

    for (int i = t; i < 32 * 64 / 4; i += 256) ((float4*)W2s)[i] = ((const float4*)W2)[i];
    for (int i = t; i < 64 * 64 / 4; i += 256) ((float4*)Wgs)[i] = ((const float4*)Wg)[i];
    for (int i = t; i < 64 * 8; i += 256) {
        int r = i % 64, k4 = i / 64;
        int row = row0 + r;
        float4 v = {0.f, 0.f, 0.f, 0.f};
        if (row < n) v = ((const float4*)(T + (size_t)row * 32))[k4];
        xs[4 * k4 + 0][r] = v.x;
        xs[4 * k4 + 1][r] = v.y;
        xs[4 * k4 + 2][r] = v.z;
        xs[4 * k4 + 3][r] = v.w;
    }
    __syncthreads();

    int tx = t % 16, ty = t / 16;
    {
        float acc[4][4] = {};
#pragma unroll 4
        for (int k = 0; k < 32; ++k) {
            float4 xv = *(const float4*)&xs[k][ty * 4];
            float4 wv = *(const float4*)&W2s[k * 64 + tx * 4];
            float xr[4] = {xv.x, xv.y, xv.z, xv.w};
            float wr[4] = {wv.x, wv.y, wv.z, wv.w};
#pragma unroll
            for (int i = 0; i < 4; ++i)
#pragma unroll
                for (int j = 0; j < 4; ++j)
                    acc[i][j] = fmaf(xr[i], wr[j], acc[i][j]);
        }
#pragma unroll
        for (int i = 0; i < 4; ++i) {
            int row = row0 + ty * 4 + i;
            float s = (row < n) ? dinv[row] : 0.f;
#pragma unroll
            for (int j = 0; j < 4; ++j)
                hs[4 * tx + j][ty * 4 + i] = fmaxf(fmaf(acc[i][j], s, b2[4 * tx + j]), 0.f);
        }
    }
    __syncthreads();

    float acc[4][4] = {};
#pragma unroll 4
    for (int k = 0; k < 64; ++k) {
        float4 xv = *(const float4*)&hs[k][ty * 4];
        float4 wv = *(const float4*)&Wgs[k * 64 + tx * 4];
        float xr[4] = {xv.x, xv.y, xv.z, xv.w};
        float wr[4] = {wv.x, wv.y, wv.z, wv.w};
#pragma unroll
        for (int i = 0; i < 4; ++i)
#pragma unroll
            for (int j = 0; j < 4; ++j)
                acc[i][j] = fmaf(xr[i], wr[j], acc[i][j]);
    }
#pragma unroll
    for (int i = 0; i < 4; ++i) {
        int row = row0 + ty * 4 + i;
        if (row >= n) continue;
        float4 o = {acc[i][0], acc[i][1], acc[i][2], acc[i][3]};
        ((float4*)(A1 + (size_t)row * 64))[tx] = o;
    }
    {
        int hd = tx >> 2;
        float as0 = att_src[4 * tx + 0], as1 = att_src[4 * tx + 1];
        float as2 = att_src[4 * tx + 2], as3 = att_src[4 * tx + 3];
        float ad0 = att_dst[4 * tx + 0], ad1 = att_dst[4 * tx + 1];
        float ad2 = att_dst[4 * tx + 2], ad3 = att_dst[4 * tx + 3];
#pragma unroll
        for (int i = 0; i < 4; ++i) {
            float ps = acc[i][0] * as0 + acc[i][1] * as1 + acc[i][2] * as2 + acc[i][3] * as3;
            float pd = acc[i][0] * ad0 + acc[i][1] * ad1 + acc[i][2] * ad2 + acc[i][3] * ad3;
            ps += __shfl_xor(ps, 1); pd += __shfl_xor(pd, 1);
            ps += __shfl_xor(ps, 2); pd += __shfl_xor(pd, 2);
            int row = row0 + ty * 4 + i;
            if ((tx & 3) == 0 && row < n) {
                a_sT[(size_t)hd * n + row] = ps;
                a_dT[(size_t)hd * n + row] = pd;
            }
        }
    }
}

// ---------------- 32-dim aggregations (unchanged from best-known) ----------------
template <int F, int MODE, bool RES>
__global__ void gcn_agg_w(const float* __restrict__ Hs, const int* __restrict__ row_ptr,
                          const int* __restrict__ csr, const float* __restrict__ dinv,
                          const float* __restrict__ bias, const float* __restrict__ res,
                          float* __restrict__ out, int n) {
    constexpr int CG = F / 4;
    constexpr int SLOTS = 64 / CG;
    int idx = blockIdx.x * blockDim.x + threadIdx.x;
    int v = idx >> 6;
    int lane = idx & 63;
    if (v >= n) return;
    int cg = lane % CG;
    int slot = lane / CG;
    const float4* H4 = (const float4*)Hs;

    float4 acc = {0.f, 0.f, 0.f, 0.f};
    if (slot == 0) acc = H4[(size_t)v * CG + cg];  // self loop

    int beg = row_ptr[v], end = row_ptr[v + 1];
    int iters = (end - beg + SLOTS - 1) / SLOTS;
    int e = beg + slot;
    bool val = e < end;
    int u = val ? csr[e] : v;
    float4 h = H4[(size_t)u * CG + cg];
    for (int i = 0; i < iters; ++i) {
        int en = e + SLOTS;
        bool valn = en < end;
        int un = valn ? csr[en] : v;
        float4 hn = H4[(size_t)un * CG + cg];
        float m = val ? 1.f : 0.f;
        acc.x = fmaf(m, h.x, acc.x);
        acc.y = fmaf(m, h.y, acc.y);
        acc.z = fmaf(m, h.z, acc.z);
        acc.w = fmaf(m, h.w, acc.w);
        e = en; val = valn; h = hn;
    }
    for (int off = CG; off < 64; off <<= 1) {
        acc.x += __shfl_xor(acc.x, off);
        acc.y += __shfl_xor(acc.y, off);
        acc.z += __shfl_xor(acc.z, off);
        acc.w += __shfl_xor(acc.w, off);
    }
    if (slot == 0) {
        float4 o;
        if (MODE == 2) {
            o = acc;
        } else {
            float dv = dinv[v];
            o.x = fmaxf(fmaf(dv, acc.x, bias[4 * cg + 0]), 0.f);
            o.y = fmaxf(fmaf(dv, acc.y, bias[4 * cg + 1]), 0.f);
            o.z = fmaxf(fmaf(dv, acc.z, bias[4 * cg + 2]), 0.f);
            o.w = fmaxf(fmaf(dv, acc.w, bias[4 * cg + 3]), 0.f);
            if (MODE == 1) { o.x *= dv; o.y *= dv; o.z *= dv; o.w *= dv; }
            if (RES) {
                const float4 r = ((const float4*)res)[(size_t)v * CG + cg];
                o.x += r.x; o.y += r.y; o.z += r.z; o.w += r.w;
            }
        }
        ((float4*)out)[(size_t)v * CG + cg] = o;
    }
}

// ---------------- 64-dim aggregations, XCD channel-partitioned ----------------
// One wave per (node, group); group = blockIdx%4 so each group lands on an XCD
// pair (blockIdx%8 -> XCD round-robin) and fetches only its 64B line per row.
// lane = slot*4 + c: 16 edge slots x 4 float-quads (one 64B line per edge).

// GCN3: out = relu(dinv*acc + bias) + res, channel slice [g*16, g*16+16)
__global__ void __launch_bounds__(256)
gcn_agg_h(const float* __restrict__ Hs, const int* __restrict__ row_ptr,
          const int* __restrict__ csr, const float* __restrict__ dinv,
          const float* __restrict__ bias, const float* __restrict__ res,
          float* __restrict__ out, int n) {
    int wid = threadIdx.x >> 6, lane = threadIdx.x & 63;
    int g = blockIdx.x & 3;
    int v = (blockIdx.x >> 2) * 4 + wid;
    if (v >= n) return;
    int c = lane & 3, slot = lane >> 2;
    const float4* H4 = (const float4*)Hs;

    float4 acc = {0.f, 0.f, 0.f, 0.f};
    if (slot == 0) acc = H4[(size_t)v * 16 + g * 4 + c];  // self loop (pre-scaled)

    int beg = row_ptr[v], end = row_ptr[v + 1];
    int iters = (end - beg + 15) >> 4;
    int e = beg + slot;
    bool val = e < end;
    int u = val ? csr[e] : v;
    float4 h = H4[(size_t)u * 16 + g * 4 + c];
    for (int i = 0; i < iters; ++i) {
        int en = e + 16;
        bool valn = en < end;
        int un = valn ? csr[en] : v;
        float4 hn = H4[(size_t)un * 16 + g * 4 + c];
        float m = val ? 1.f : 0.f;
        acc.x = fmaf(m, h.x, acc.x);
        acc.y = fmaf(m, h.y, acc.y);
        acc.z = fmaf(m, h.z, acc.z);
        acc.w = fmaf(m, h.w, acc.w);
        e = en; val = valn; h = hn;
    }
    for (int off = 4; off < 64; off <<= 1) {
        acc.x += __shfl_xor(acc.x, off);
        acc.y += __shfl_xor(acc.y, off);
        acc.z += __shfl_xor(acc.z, off);
        acc.w += __shfl_xor(acc.w, off);
    }
    if (slot == 0) {
        float dv = dinv[v];
        const float4 r = ((const float4*)res)[(size_t)v * 16 + g * 4 + c];
        float4 o;
        o.x = fmaxf(fmaf(dv, acc.x, bias[g * 16 + 4 * c + 0]), 0.f) + r.x;
        o.y = fmaxf(fmaf(dv, acc.y, bias[g * 16 + 4 * c + 1]), 0.f) + r.y;
        o.z = fmaxf(fmaf(dv, acc.z, bias[g * 16 + 4 * c + 2]), 0.f) + r.z;
        o.w = fmaxf(fmaf(dv, acc.w, bias[g * 16 + 4 * c + 3]), 0.f) + r.w;
        ((float4*)out)[(size_t)v * 16 + g * 4 + c] = o;
    }
}

// GAT: group == head (16 channels == one head). Per-head softmax is
// self-contained. FINAL writes per-(v,head) partial dot with Wl.
template <bool FINAL>
__global__ void __launch_bounds__(256)
gat_agg_h(const float* __restrict__ H, const int* __restrict__ row_ptr,
          const int* __restrict__ csr, const float* __restrict__ a_sT,
          const float* __restrict__ a_dT, const float* __restrict__ bias,
          const float* __restrict__ Wl, float* __restrict__ out, int n) {
    int wid = threadIdx.x >> 6, lane = threadIdx.x & 63;
    int hd = blockIdx.x & 3;
    int v = (blockIdx.x >> 2) * 4 + wid;
    if (v >= n) return;
    int c = lane & 3, slot = lane >> 2;
    const float4* H4 = (const float4*)H;
    const float* asb = a_sT + (size_t)hd * n;

    float adv = a_dT[(size_t)hd * n + v];
    float l = 0.f;
    float4 acc = {0.f, 0.f, 0.f, 0.f};
    if (slot == 0) {  // self edge
        float e0 = asb[v] + adv;
        e0 = (e0 >= 0.f) ? e0 : 0.2f * e0;
        float p = __expf(e0);
        l = p;
        float4 h = H4[(size_t)v * 16 + hd * 4 + c];
        acc.x = p * h.x; acc.y = p * h.y; acc.z = p * h.z; acc.w = p * h.w;
    }
    int beg = row_ptr[v], end = row_ptr[v + 1];
    int iters = (end - beg + 15) >> 4;
    int e = beg + slot;
    bool val = e < end;
    int u = val ? csr[e] : v;
    float4 h = H4[(size_t)u * 16 + hd * 4 + c];
    float as = asb[u];
    for (int i = 0; i < iters; ++i) {
        int en = e + 16;
        bool valn = en < end;
        int un = valn ? csr[en] : v;
        float4 hn = H4[(size_t)un * 16 + hd * 4 + c];
        float asn = asb[un];
        float ev = as + adv;
        ev = (ev >= 0.f) ? ev : 0.2f * ev;
        float p = val ? __expf(ev) : 0.f;
        l += p;
        acc.x = fmaf(p, h.x, acc.x);
        acc.y = fmaf(p, h.y, acc.y);
        acc.z = fmaf(p, h.z, acc.z);
        acc.w = fmaf(p, h.w, acc.w);
        e = en; val = valn; h = hn; as = asn;
    }
    for (int off = 4; off < 64; off <<= 1) {
        l += __shfl_xor(l, off);
        acc.x += __shfl_xor(acc.x, off);
        acc.y += __shfl_xor(acc.y, off);
        acc.z += __shfl_xor(acc.z, off);
        acc.w += __shfl_xor(acc.w, off);
    }
    float rl = 1.0f / (l + 1e-16f);
    if (!FINAL) {
        if (slot == 0) {
            float4 o;
            o.x = fmaxf(fmaf(acc.x, rl, bias[hd * 16 + 4 * c + 0]), 0.f);
            o.y = fmaxf(fmaf(acc.y, rl, bias[hd * 16 + 4 * c + 1]), 0.f);
            o.z = fmaxf(fmaf(acc.z, rl, bias[hd * 16 + 4 * c + 2]), 0.f);
            o.w = fmaxf(fmaf(acc.w, rl, bias[hd * 16 + 4 * c + 3]), 0.f);
            ((float4*)out)[(size_t)v * 16 + hd * 4 + c] = o;
        }
    } else {
        float p = 0.f;
        if (slot == 0) {
            p = fmaxf(fmaf(acc.x, rl, bias[hd * 16 + 4 * c + 0]), 0.f) * Wl[hd * 16 + 4 * c + 0]
              + fmaxf(fmaf(acc.y, rl, bias[hd * 16 + 4 * c + 1]), 0.f) * Wl[hd * 16 + 4 * c + 1]
              + fmaxf(fmaf(acc.z, rl, bias[hd * 16 + 4 * c + 2]), 0.f) * Wl[hd * 16 + 4 * c + 2]
              + fmaxf(fmaf(acc.w, rl, bias[hd * 16 + 4 * c + 3]), 0.f) * Wl[hd * 16 + 4 * c + 3];
        }
        p += __shfl_xor(p, 1);
        p += __shfl_xor(p, 2);
        if (lane == 0) out[(size_t)v * 4 + hd] = p;  // partial per (v,head)
    }
}

// combine per-head partials: out[v] = relu(sum_h part[v,h] + bl)
__global__ void final_sum(const float* __restrict__ part, const float* __restrict__ bl,
                          float* __restrict__ out, int n) {
    int v = blockIdx.x * blockDim.x + threadIdx.x;
    if (v < n) {
        float4 p = ((const float4*)part)[v];
        out[v] = fmaxf(p.x + p.y + p.z + p.w + bl[0], 0.f);
    }
}

// ---------------- launch ----------------

extern "C" void kernel_launch(void* const* d_in, const int* in_sizes, int n_in,
                              void* d_out, int out_size, void* d_ws, size_t ws_size,
                              hipStream_t stream) {
    const float* x     = (const float*)d_in[0];
    const int*   ei    = (const int*)d_in[1];
    const float* W1    = (const float*)d_in[2];
    const float* b1    = (const float*)d_in[3];
    const float* W2    = (const float*)d_in[4];
    const float* b2    = (const float*)d_in[5];
    const float* W3    = (const float*)d_in[6];
    const float* b3    = (const float*)d_in[7];
    const float* Wg    = (const float*)d_in[8];
    const float* att_s = (const float*)d_in[9];
    const float* att_d = (const float*)d_in[10];
    const float* bg    = (const float*)d_in[11];
    const float* Wl    = (const float*)d_in[12];
    const float* bl    = (const float*)d_in[13];
    float* out = (float*)d_out;

    int n = in_sizes[0] / KIN;  // 100000
    int E = in_sizes[1] / 2;    // 1600000
    const int* srcp = ei;
    const int* dstp = ei + E;

    char* w = (char*)d_ws;
    auto alloc = [&](size_t bytes) -> void* {
        void* p = (void*)w;
        w += (bytes + 255) & ~(size_t)255;
        return p;
    };
    int*   cnt     = (int*)alloc((size_t)n * 4);
    int*   row_ptr = (int*)alloc((size_t)(n + 1) * 4);
    int*   rank    = (int*)alloc((size_t)E * 4);
    int*   bsum    = (int*)alloc(512 * 4);
    int*   bpre    = (int*)alloc(512 * 4);
    int*   csr     = (int*)alloc((size_t)E * 4);
    float* dinv    = (float*)alloc((size_t)n * 4);
    float* a_sT    = (float*)alloc((size_t)n * 4 * 4);
    float* a_dT    = (float*)alloc((size_t)n * 4 * 4);
    float* part    = (float*)alloc((size_t)n * 4 * 4);
    float* bufA    = (float*)alloc((size_t)n * 64 * 4);
    float* bufB    = (float*)alloc((size_t)n * 64 * 4);
    float* bufC    = (float*)alloc((size_t)n * 64 * 4);

    hipMemsetAsync(cnt, 0, (size_t)n * 4, stream);

    int nb = (n + 255) / 256;
    int eb = (E + 255) / 256;
    count_rank<<<eb, 256, 0, stream>>>(dstp, cnt, rank, E);
    scan_reduce_dinv<<<nb, 256, 0, stream>>>(cnt, bsum, dinv, n);
    scan_blocksums<<<1, 512, 0, stream>>>(bsum, bpre, nb);
    scan_scatter<<<nb, 256, 0, stream>>>(cnt, bpre, row_ptr, n, E);
    fill_csr<<<eb, 256, 0, stream>>>(srcp, dstp, rank, row_ptr, csr, E);

    int agg_blocks = (n * 64 + 255) / 256;
    int gemm_blocks = (n + 63) / 64;
    int hblocks = ((n + 3) / 4) * 4;   // (node-chunk, group) waves, group = blockIdx%4

    // Layer 1: GCN 128->32. H1s = dinv⊙(X@W1); agg emits G = dinv*relu(dinv*agg+b1)
    gemm_tile<128, 32, 64, 128, true, false, false><<<gemm_blocks, 128, 0, stream>>>(
        x, W1, dinv, nullptr, nullptr, nullptr, nullptr, nullptr, bufA, n);
    gcn_agg_w<32, 1, false><<<agg_blocks, 256, 0, stream>>>(bufA, row_ptr, csr, dinv, b1, nullptr, bufB, n);
    // Layer 2 agg in 32-dim (raw sum T)
    gcn_agg_w<32, 2, false><<<agg_blocks, 256, 0, stream>>>(bufB, row_ptr, csr, nullptr, nullptr, nullptr, bufA, n);
    // Fused: h2 = relu(dinv*T@W2+b2) (LDS only); A1 = h2@Wg; attention dots (transposed)
    gemm2_gat<<<gemm_blocks, 256, 0, stream>>>(bufA, W2, b2, dinv, Wg, att_s, att_d, a_sT, a_dT, bufB, n);
    // GAT1 aggregation, head-partitioned
    gat_agg_h<false><<<hblocks, 256, 0, stream>>>(bufB, row_ptr, csr, a_sT, a_dT, bg, nullptr, bufC, n);
    // GCN 3 + residual, channel-partitioned
    gemm_tile<64, 64, 64, 256, true, false, false><<<gemm_blocks, 256, 0, stream>>>(
        bufC, W3, dinv, nullptr, nullptr, nullptr, nullptr, nullptr, bufA, n);
    gcn_agg_h<<<hblocks, 256, 0, stream>>>(bufA, row_ptr, csr, dinv, b3, bufC, bufB, n);
    // GAT 2 (gemm + fused attention dots, transposed)
    gemm_tile<64, 64, 64, 256, false, false, true><<<gemm_blocks, 256, 0, stream>>>(
        bufB, Wg, nullptr, nullptr, att_s, att_d, a_sT, a_dT, bufA, n);
    // GAT2 aggregation -> per-head partial dots, then combine
    gat_agg_h<true><<<hblocks, 256, 0, stream>>>(bufA, row_ptr, csr, a_sT, a_dT, bg, Wl, part, n);
    final_sum<<<nb, 256, 0, stream>>>(part, bl, out, n);
}

// Round 9
// 580.705 us; speedup vs baseline: 1.3830x; 1.3830x over previous
//
#include <hip/hip_runtime.h>
#include <math.h>

constexpr int KIN = 128;   // IN_F

// ---------------- graph build: MSD bucket sort (dst>>9), then per-bucket
// counting sort by dst&511. Produces csr, row_ptr, dinv with no global
// atomics and no scattered 4B stores. ----------------

// per-chunk histogram of dst>>9; hist_g layout [digit * NB + block]
__global__ void rx_hist(const int* __restrict__ dst, int* __restrict__ hist_g,
                        int E, int CH, int NB, int NBKT) {
    __shared__ int h[256];
    int b = blockIdx.x;
    for (int i = threadIdx.x; i < 256; i += blockDim.x) h[i] = 0;
    __syncthreads();
    int beg = b * CH, end = min(beg + CH, E);
    for (int e = beg + threadIdx.x; e < end; e += blockDim.x)
        atomicAdd(&h[dst[e] >> 9], 1);
    __syncthreads();
    for (int d = threadIdx.x; d < NBKT; d += blockDim.x)
        hist_g[d * NB + b] = h[d];
}

// generic 3-kernel exclusive scan over m ints
__global__ void gs_reduce(const int* __restrict__ a, int* __restrict__ bsum, int m) {
    __shared__ int s[256];
    int t = threadIdx.x;
    int i = blockIdx.x * 256 + t;
    s[t] = (i < m) ? a[i] : 0;
    __syncthreads();
    for (int off = 128; off > 0; off >>= 1) {
        if (t < off) s[t] += s[t + off];
        __syncthreads();
    }
    if (t == 0) bsum[blockIdx.x] = s[0];
}

__global__ void gs_blocksums(const int* __restrict__ bsum, int* __restrict__ bpre, int nb) {
    __shared__ int s[512];
    int t = threadIdx.x;
    int val = (t < nb) ? bsum[t] : 0;
    s[t] = val;
    __syncthreads();
    for (int off = 1; off < 512; off <<= 1) {
        int x = (t >= off) ? s[t - off] : 0;
        __syncthreads();
        s[t] += x;
        __syncthreads();
    }
    if (t < nb) bpre[t] = s[t] - val;  // exclusive
}

__global__ void gs_scatter(const int* __restrict__ a, const int* __restrict__ bpre,
                           int* __restrict__ out, int m) {
    __shared__ int s[256];
    int t = threadIdx.x;
    int i = blockIdx.x * 256 + t;
    int val = (i < m) ? a[i] : 0;
    s[t] = val;
    __syncthreads();
    for (int off = 1; off < 256; off <<= 1) {
        int x = (t >= off) ? s[t - off] : 0;
        __syncthreads();
        s[t] += x;
        __syncthreads();
    }
    if (i < m) out[i] = bpre[blockIdx.x] + s[t] - val;
}

// scatter edges into bucket order; per-(block,bucket) writes are sequential runs
__global__ void rx_scatter(const int* __restrict__ src, const int* __restrict__ dst,
                           const int* __restrict__ excl, int* __restrict__ s1,
                           int* __restrict__ d1, int E, int CH, int NB, int NBKT) {
    __shared__ int offs[256];
    int b = blockIdx.x;
    for (int d = threadIdx.x; d < NBKT; d += blockDim.x)
        offs[d] = excl[d * NB + b];
    __syncthreads();
    int beg = b * CH, end = min(beg + CH, E);
    for (int e = beg + threadIdx.x; e < end; e += blockDim.x) {
        int dd = dst[e];
        int pos = atomicAdd(&offs[dd >> 9], 1);
        s1[pos] = src[e];
        d1[pos] = dd;
    }
}

// one block per bucket: counting sort by dst&511 -> csr; also row_ptr + dinv
__global__ void __launch_bounds__(512)
bucket_sort(const int* __restrict__ s1, const int* __restrict__ d1,
            const int* __restrict__ excl, int* __restrict__ csr,
            int* __restrict__ row_ptr, float* __restrict__ dinv,
            int E, int NB, int NBKT, int n) {
    __shared__ int hist[512];
    __shared__ int scan[512];
    __shared__ int offs[512];
    int b = blockIdx.x, t = threadIdx.x;
    int base = excl[b * NB];
    int endb = (b + 1 < NBKT) ? excl[(b + 1) * NB] : E;
    hist[t] = 0;
    __syncthreads();
    for (int i = base + t; i < endb; i += 512)
        atomicAdd(&hist[d1[i] & 511], 1);
    __syncthreads();
    int v = hist[t];
    scan[t] = v;
    __syncthreads();
    for (int off = 1; off < 512; off <<= 1) {
        int x = (t >= off) ? scan[t - off] : 0;
        __syncthreads();
        scan[t] += x;
        __syncthreads();
    }
    int ex = scan[t] - v;  // exclusive prefix within bucket
    offs[t] = ex;
    int node = b * 512 + t;
    if (node < n) {
        row_ptr[node] = base + ex;
        dinv[node] = 1.0f / sqrtf((float)(v + 1));  // +1 self loop
    }
    if (b == NBKT - 1 && t == 0) row_ptr[n] = E;
    __syncthreads();
    for (int i = base + t; i < endb; i += 512) {
        int dd = d1[i];
        int pos = atomicAdd(&offs[dd & 511], 1);
        csr[base + pos] = s1[i];
    }
}

// ---------------- tiled register-blocked GEMM (R7 shape) ----------------
template <int K, int F, int BM, int THREADS, bool SCALE, bool BRELU, bool ATT>
__global__ void __launch_bounds__(THREADS)
gemm_tile(const float* __restrict__ in, const float* __restrict__ W,
          const float* __restrict__ dinv, const float* __restrict__ bias,
          const float* __restrict__ att_src, const float* __restrict__ att_dst,
          float* __restrict__ a_s, float* __restrict__ a_d,
          float* __restrict__ out, int n) {
    constexpr int TM = 4, TN = 4;
    constexpr int TX = F / TN;
    constexpr int TY = BM / TM;
    static_assert(THREADS == TX * TY, "thread count mismatch");
    constexpr int K4 = K / 4;
    __shared__ float xs[K][BM];
    __shared__ float Ws[K * F];
    int t = threadIdx.x;
    int row0 = blockIdx.x * BM;

    for (int i = t; i < K * F / 4; i += THREADS)
        ((float4*)Ws)[i] = ((const float4*)W)[i];

    for (int i = t; i < BM * K4; i += THREADS) {
        int r = i % BM, k4 = i / BM;
        int row = row0 + r;
        float4 v = {0.f, 0.f, 0.f, 0.f};
        if (row < n) v = ((const float4*)(in + (size_t)row * K))[k4];
        xs[4 * k4 + 0][r] = v.x;
        xs[4 * k4 + 1][r] = v.y;
        xs[4 * k4 + 2][r] = v.z;
        xs[4 * k4 + 3][r] = v.w;
    }
    __syncthreads();

    int tx = t % TX, ty = t / TX;
    float acc[TM][TN] = {};
#pragma unroll 4
    for (int k = 0; k < K; ++k) {
        float4 xv = *(const float4*)&xs[k][ty * TM];
        float4 wv = *(const float4*)&Ws[k * F + tx * TN];
        float xr[4] = {xv.x, xv.y, xv.z, xv.w};
        float wr[4] = {wv.x, wv.y, wv.z, wv.w};
#pragma unroll
        for (int i = 0; i < TM; ++i)
#pragma unroll
            for (int j = 0; j < TN; ++j)
                acc[i][j] = fmaf(xr[i], wr[j], acc[i][j]);
    }

#pragma unroll
    for (int i = 0; i < TM; ++i) {
        int row = row0 + ty * TM + i;
        if (row >= n) continue;
        float s = SCALE ? dinv[row] : 1.0f;
        float4 o;
        if (BRELU) {
            o.x = fmaxf(fmaf(acc[i][0], s, bias[4 * tx + 0]), 0.f);
            o.y = fmaxf(fmaf(acc[i][1], s, bias[4 * tx + 1]), 0.f);
            o.z = fmaxf(fmaf(acc[i][2], s, bias[4 * tx + 2]), 0.f);
            o.w = fmaxf(fmaf(acc[i][3], s, bias[4 * tx + 3]), 0.f);
        } else {
            o.x = acc[i][0] * s; o.y = acc[i][1] * s;
            o.z = acc[i][2] * s; o.w = acc[i][3] * s;
        }
        ((float4*)(out + (size_t)row * F))[tx] = o;
    }
    if (ATT) {
        int hd = tx >> 2;
        float as0 = att_src[4 * tx + 0], as1 = att_src[4 * tx + 1];
        float as2 = att_src[4 * tx + 2], as3 = att_src[4 * tx + 3];
        float ad0 = att_dst[4 * tx + 0], ad1 = att_dst[4 * tx + 1];
        float ad2 = att_dst[4 * tx + 2], ad3 = att_dst[4 * tx + 3];
#pragma unroll
        for (int i = 0; i < TM; ++i) {
            float ps = acc[i][0] * as0 + acc[i][1] * as1 + acc[i][2] * as2 + acc[i][3] * as3;
            float pd = acc[i][0] * ad0 + acc[i][1] * ad1 + acc[i][2] * ad2 + acc[i][3] * ad3;
            ps += __shfl_xor(ps, 1); pd += __shfl_xor(pd, 1);
            ps += __shfl_xor(ps, 2); pd += __shfl_xor(pd, 2);
            int row = row0 + ty * TM + i;
            if ((tx & 3) == 0 && row < n) {
                a_s[row * 4 + hd] = ps;
                a_d[row * 4 + hd] = pd;
            }
        }
    }
}

// ---------------- fused layer2-GEMM + GAT1-GEMM (R7 shape) ----------------
__global__ void __launch_bounds__(256)
gemm2_gat(const float* __restrict__ T, const float* __restrict__ W2,
          const float* __restrict__ b2, const float* __restrict__ dinv,
          const float* __restrict__ Wg, const float* __restrict__ att_src,
          const float* __restrict__ att_dst, float* __restrict__ a_s,
          float* __restrict__ a_d, float* __restrict__ A1, int n) {
    __shared__ float xs[32][64];
    __shared__ float W2s[32 * 64];
    __shared__ float Wgs[64 * 64];
    __shared__ float hs[64][68];
    int t = threadIdx.x;
    int row0 = blockIdx.x * 64;

    for (int i = t; i < 32 * 64 / 4; i += 256) ((float4*)W2s)[i] = ((const float4*)W2)[i];
    for (int i = t; i < 64 * 64 / 4; i += 256) ((float4*)Wgs)[i] = ((const float4*)Wg)[i];
    for (int i = t; i < 64 * 8; i += 256) {
        int r = i % 64, k4 = i / 64;
        int row = row0 + r;
        float4 v = {0.f, 0.f, 0.f, 0.f};
        if (row < n) v = ((const float4*)(T + (size_t)row * 32))[k4];
        xs[4 * k4 + 0][r] = v.x;
        xs[4 * k4 + 1][r] = v.y;
        xs[4 * k4 + 2][r] = v.z;
        xs[4 * k4 + 3][r] = v.w;
    }
    __syncthreads();

    int tx = t % 16, ty = t / 16;
    {
        float acc[4][4] = {};
#pragma unroll 4
        for (int k = 0; k < 32; ++k) {
            float4 xv = *(const float4*)&xs[k][ty * 4];
            float4 wv = *(const float4*)&W2s[k * 64 + tx * 4];
            float xr[4] = {xv.x, xv.y, xv.z, xv.w};
            float wr[4] = {wv.x, wv.y, wv.z, wv.w};
#pragma unroll
            for (int i = 0; i < 4; ++i)
#pragma unroll
                for (int j = 0; j < 4; ++j)
                    acc[i][j] = fmaf(xr[i], wr[j], acc[i][j]);
        }
#pragma unroll
        for (int i = 0; i < 4; ++i) {
            int row = row0 + ty * 4 + i;
            float s = (row < n) ? dinv[row] : 0.f;
#pragma unroll
            for (int j = 0; j < 4; ++j)
                hs[4 * tx + j][ty * 4 + i] = fmaxf(fmaf(acc[i][j], s, b2[4 * tx + j]), 0.f);
        }
    }
    __syncthreads();

    float acc[4][4] = {};
#pragma unroll 4
    for (int k = 0; k < 64; ++k) {
        float4 xv = *(const float4*)&hs[k][ty * 4];
        float4 wv = *(const float4*)&Wgs[k * 64 + tx * 4];
        float xr[4] = {xv.x, xv.y, xv.z, xv.w};
        float wr[4] = {wv.x, wv.y, wv.z, wv.w};
#pragma unroll
        for (int i = 0; i < 4; ++i)
#pragma unroll
            for (int j = 0; j < 4; ++j)
                acc[i][j] = fmaf(xr[i], wr[j], acc[i][j]);
    }
#pragma unroll
    for (int i = 0; i < 4; ++i) {
        int row = row0 + ty * 4 + i;
        if (row >= n) continue;
        float4 o = {acc[i][0], acc[i][1], acc[i][2], acc[i][3]};
        ((float4*)(A1 + (size_t)row * 64))[tx] = o;
    }
    {
        int hd = tx >> 2;
        float as0 = att_src[4 * tx + 0], as1 = att_src[4 * tx + 1];
        float as2 = att_src[4 * tx + 2], as3 = att_src[4 * tx + 3];
        float ad0 = att_dst[4 * tx + 0], ad1 = att_dst[4 * tx + 1];
        float ad2 = att_dst[4 * tx + 2], ad3 = att_dst[4 * tx + 3];
#pragma unroll
        for (int i = 0; i < 4; ++i) {
            float ps = acc[i][0] * as0 + acc[i][1] * as1 + acc[i][2] * as2 + acc[i][3] * as3;
            float pd = acc[i][0] * ad0 + acc[i][1] * ad1 + acc[i][2] * ad2 + acc[i][3] * ad3;
            ps += __shfl_xor(ps, 1); pd += __shfl_xor(pd, 1);
            ps += __shfl_xor(ps, 2); pd += __shfl_xor(pd, 2);
            int row = row0 + ty * 4 + i;
            if ((tx & 3) == 0 && row < n) {
                a_s[row * 4 + hd] = ps;
                a_d[row * 4 + hd] = pd;
            }
        }
    }
}

// ---------------- aggregation kernels (R7 shape, depth-1 pipeline) ----------------
// MODE 0: out = relu(dinv*acc + b) (+res)   MODE 1: out = dinv*relu(dinv*acc + b)
// MODE 2: out = acc (raw sum)
template <int F, int MODE, bool RES>
__global__ void gcn_agg_w(const float* __restrict__ Hs, const int* __restrict__ row_ptr,
                          const int* __restrict__ csr, const float* __restrict__ dinv,
                          const float* __restrict__ bias, const float* __restrict__ res,
                          float* __restrict__ out, int n) {
    constexpr int CG = F / 4;
    constexpr int SLOTS = 64 / CG;
    int idx = blockIdx.x * blockDim.x + threadIdx.x;
    int v = idx >> 6;
    int lane = idx & 63;
    if (v >= n) return;
    int cg = lane % CG;
    int slot = lane / CG;
    const float4* H4 = (const float4*)Hs;

    float4 acc = {0.f, 0.f, 0.f, 0.f};
    if (slot == 0) acc = H4[(size_t)v * CG + cg];  // self loop

    int beg = row_ptr[v], end = row_ptr[v + 1];
    int iters = (end - beg + SLOTS - 1) / SLOTS;
    int e = beg + slot;
    bool val = e < end;
    int u = val ? csr[e] : v;
    float4 h = H4[(size_t)u * CG + cg];
    for (int i = 0; i < iters; ++i) {
        int en = e + SLOTS;
        bool valn = en < end;
        int un = valn ? csr[en] : v;
        float4 hn = H4[(size_t)un * CG + cg];
        float m = val ? 1.f : 0.f;
        acc.x = fmaf(m, h.x, acc.x);
        acc.y = fmaf(m, h.y, acc.y);
        acc.z = fmaf(m, h.z, acc.z);
        acc.w = fmaf(m, h.w, acc.w);
        e = en; val = valn; h = hn;
    }
    for (int off = CG; off < 64; off <<= 1) {
        acc.x += __shfl_xor(acc.x, off);
        acc.y += __shfl_xor(acc.y, off);
        acc.z += __shfl_xor(acc.z, off);
        acc.w += __shfl_xor(acc.w, off);
    }
    if (slot == 0) {
        float4 o;
        if (MODE == 2) {
            o = acc;
        } else {
            float dv = dinv[v];
            o.x = fmaxf(fmaf(dv, acc.x, bias[4 * cg + 0]), 0.f);
            o.y = fmaxf(fmaf(dv, acc.y, bias[4 * cg + 1]), 0.f);
            o.z = fmaxf(fmaf(dv, acc.z, bias[4 * cg + 2]), 0.f);
            o.w = fmaxf(fmaf(dv, acc.w, bias[4 * cg + 3]), 0.f);
            if (MODE == 1) { o.x *= dv; o.y *= dv; o.z *= dv; o.w *= dv; }
            if (RES) {
                const float4 r = ((const float4*)res)[(size_t)v * CG + cg];
                o.x += r.x; o.y += r.y; o.z += r.z; o.w += r.w;
            }
        }
        ((float4*)out)[(size_t)v * CG + cg] = o;
    }
}

template <bool FINAL>
__global__ void gat_agg_w(const float* __restrict__ H, const int* __restrict__ row_ptr,
                          const int* __restrict__ csr, const float* __restrict__ a_s,
                          const float* __restrict__ a_d, const float* __restrict__ bias,
                          const float* __restrict__ Wl, const float* __restrict__ bl,
                          float* __restrict__ out, int n) {
    int idx = blockIdx.x * blockDim.x + threadIdx.x;
    int v = idx >> 6;
    int lane = idx & 63;
    if (v >= n) return;
    int cg = lane & 15;
    int slot = lane >> 4;
    int hd = cg >> 2;
    const float4* H4 = (const float4*)H;

    float adv = a_d[v * 4 + hd];
    float l = 0.f;
    float4 acc = {0.f, 0.f, 0.f, 0.f};
    if (slot == 0) {  // self edge
        float e0 = a_s[v * 4 + hd] + adv;
        e0 = (e0 >= 0.f) ? e0 : 0.2f * e0;
        float p = __expf(e0);
        l = p;
        float4 h = H4[(size_t)v * 16 + cg];
        acc.x = p * h.x; acc.y = p * h.y; acc.z = p * h.z; acc.w = p * h.w;
    }
    int beg = row_ptr[v], end = row_ptr[v + 1];
    int iters = (end - beg + 3) >> 2;
    int e = beg + slot;
    bool val = e < end;
    int u = val ? csr[e] : v;
    float4 h = H4[(size_t)u * 16 + cg];
    float as = a_s[u * 4 + hd];
    for (int i = 0; i < iters; ++i) {
        int en = e + 4;
        bool valn = en < end;
        int un = valn ? csr[en] : v;
        float4 hn = H4[(size_t)un * 16 + cg];
        float asn = a_s[un * 4 + hd];
        float ev = as + adv;
        ev = (ev >= 0.f) ? ev : 0.2f * ev;
        float p = val ? __expf(ev) : 0.f;
        l += p;
        acc.x = fmaf(p, h.x, acc.x);
        acc.y = fmaf(p, h.y, acc.y);
        acc.z = fmaf(p, h.z, acc.z);
        acc.w = fmaf(p, h.w, acc.w);
        e = en; val = valn; h = hn; as = asn;
    }
    for (int off = 16; off < 64; off <<= 1) {
        l += __shfl_xor(l, off);
        acc.x += __shfl_xor(acc.x, off);
        acc.y += __shfl_xor(acc.y, off);
        acc.z += __shfl_xor(acc.z, off);
        acc.w += __shfl_xor(acc.w, off);
    }
    float rl = 1.0f / (l + 1e-16f);
    if (!FINAL) {
        if (slot == 0) {
            float4 o;
            o.x = fmaxf(fmaf(acc.x, rl, bias[4 * cg + 0]), 0.f);
            o.y = fmaxf(fmaf(acc.y, rl, bias[4 * cg + 1]), 0.f);
            o.z = fmaxf(fmaf(acc.z, rl, bias[4 * cg + 2]), 0.f);
            o.w = fmaxf(fmaf(acc.w, rl, bias[4 * cg + 3]), 0.f);
            ((float4*)out)[(size_t)v * 16 + cg] = o;
        }
    } else {
        float p = fmaxf(fmaf(acc.x, rl, bias[4 * cg + 0]), 0.f) * Wl[4 * cg + 0]
                + fmaxf(fmaf(acc.y, rl, bias[4 * cg + 1]), 0.f) * Wl[4 * cg + 1]
                + fmaxf(fmaf(acc.z, rl, bias[4 * cg + 2]), 0.f) * Wl[4 * cg + 2]
                + fmaxf(fmaf(acc.w, rl, bias[4 * cg + 3]), 0.f) * Wl[4 * cg + 3];
        p += __shfl_xor(p, 1);
        p += __shfl_xor(p, 2);
        p += __shfl_xor(p, 4);
        p += __shfl_xor(p, 8);
        if (lane == 0) out[v] = fmaxf(p + bl[0], 0.f);
    }
}

// ---------------- launch ----------------

extern "C" void kernel_launch(void* const* d_in, const int* in_sizes, int n_in,
                              void* d_out, int out_size, void* d_ws, size_t ws_size,
                              hipStream_t stream) {
    const float* x     = (const float*)d_in[0];
    const int*   ei    = (const int*)d_in[1];
    const float* W1    = (const float*)d_in[2];
    const float* b1    = (const float*)d_in[3];
    const float* W2    = (const float*)d_in[4];
    const float* b2    = (const float*)d_in[5];
    const float* W3    = (const float*)d_in[6];
    const float* b3    = (const float*)d_in[7];
    const float* Wg    = (const float*)d_in[8];
    const float* att_s = (const float*)d_in[9];
    const float* att_d = (const float*)d_in[10];
    const float* bg    = (const float*)d_in[11];
    const float* Wl    = (const float*)d_in[12];
    const float* bl    = (const float*)d_in[13];
    float* out = (float*)d_out;

    int n = in_sizes[0] / KIN;  // 100000
    int E = in_sizes[1] / 2;    // 1600000
    const int* srcp = ei;
    const int* dstp = ei + E;

    // radix parameters
    int NB = 128;                      // chunks
    int CH = (E + NB - 1) / NB;        // edges per chunk
    int NBKT = (n + 511) >> 9;         // dst buckets of 512 nodes
    int M = NBKT * NB;                 // hist entries

    char* w = (char*)d_ws;
    auto alloc = [&](size_t bytes) -> void* {
        void* p = (void*)w;
        w += (bytes + 255) & ~(size_t)255;
        return p;
    };
    int*   row_ptr = (int*)alloc((size_t)(n + 1) * 4);
    int*   csr     = (int*)alloc((size_t)E * 4);
    int*   hist_g  = (int*)alloc((size_t)M * 4);
    int*   excl    = (int*)alloc((size_t)M * 4);
    int*   bsum    = (int*)alloc(512 * 4);
    int*   bpre    = (int*)alloc(512 * 4);
    float* dinv    = (float*)alloc((size_t)n * 4);
    float* a_s     = (float*)alloc((size_t)n * 4 * 4);
    float* a_d     = (float*)alloc((size_t)n * 4 * 4);
    float* bufA    = (float*)alloc((size_t)n * 64 * 4);
    float* bufB    = (float*)alloc((size_t)n * 64 * 4);
    float* bufC    = (float*)alloc((size_t)n * 64 * 4);
    // bucket-sorted edge arrays alias bufB (dead before first dense write of bufB)
    int* s1 = (int*)bufB;
    int* d1 = ((int*)bufB) + E;

    int msb = (M + 255) / 256;
    rx_hist<<<NB, 256, 0, stream>>>(dstp, hist_g, E, CH, NB, NBKT);
    gs_reduce<<<msb, 256, 0, stream>>>(hist_g, bsum, M);
    gs_blocksums<<<1, 512, 0, stream>>>(bsum, bpre, msb);
    gs_scatter<<<msb, 256, 0, stream>>>(hist_g, bpre, excl, M);
    rx_scatter<<<NB, 256, 0, stream>>>(srcp, dstp, excl, s1, d1, E, CH, NB, NBKT);
    bucket_sort<<<NBKT, 512, 0, stream>>>(s1, d1, excl, csr, row_ptr, dinv, E, NB, NBKT, n);

    int agg_blocks = (n * 64 + 255) / 256;
    int gemm_blocks = (n + 63) / 64;
    int nb = (n + 255) / 256;
    (void)nb;

    // Layer 1: GCN 128->32. H1s = dinv⊙(X@W1); agg emits G = dinv*relu(dinv*agg+b1)
    gemm_tile<128, 32, 64, 128, true, false, false><<<gemm_blocks, 128, 0, stream>>>(
        x, W1, dinv, nullptr, nullptr, nullptr, nullptr, nullptr, bufA, n);
    gcn_agg_w<32, 1, false><<<agg_blocks, 256, 0, stream>>>(bufA, row_ptr, csr, dinv, b1, nullptr, bufB, n);
    // Layer 2 agg in 32-dim (raw sum T)
    gcn_agg_w<32, 2, false><<<agg_blocks, 256, 0, stream>>>(bufB, row_ptr, csr, nullptr, nullptr, nullptr, bufA, n);
    // Fused: h2 = relu(dinv*T@W2+b2) (LDS only); A1 = h2@Wg; attention dots
    gemm2_gat<<<gemm_blocks, 256, 0, stream>>>(bufA, W2, b2, dinv, Wg, att_s, att_d, a_s, a_d, bufB, n);
    gat_agg_w<false><<<agg_blocks, 256, 0, stream>>>(bufB, row_ptr, csr, a_s, a_d, bg, nullptr, nullptr, bufC, n);
    // GCN 3 + residual
    gemm_tile<64, 64, 64, 256, true, false, false><<<gemm_blocks, 256, 0, stream>>>(
        bufC, W3, dinv, nullptr, nullptr, nullptr, nullptr, nullptr, bufA, n);
    gcn_agg_w<64, 0, true><<<agg_blocks, 256, 0, stream>>>(bufA, row_ptr, csr, dinv, b3, bufC, bufB, n);
    // GAT 2 (gemm + fused attention dots) + fused final linear
    gemm_tile<64, 64, 64, 256, false, false, true><<<gemm_blocks, 256, 0, stream>>>(
        bufB, Wg, nullptr, nullptr, att_s, att_d, a_s, a_d, bufA, n);
    gat_agg_w<true><<<agg_blocks, 256, 0, stream>>>(bufA, row_ptr, csr, a_s, a_d, bg, Wl, bl, out, n);
}